// Round 5
// baseline (177.460 us; speedup 1.0000x reference)
//
#include <hip/hip_runtime.h>

// AGMBrain: N=128, B=32, IN_FEAT=4608, grid_size=3, num_candidates=8, n_steps=2
//
// Algebraic reduction (verified rounds 1-4):
//   einsum 'bdij,bdn->bdi' factorizes: messages[b,d,i] =
//     (sum_j T[b,d,i,j]) * (sum_n s[b,d,n])
//   Step 1 closed form: m1[b,d,i] = (colsum[d] + 128 t) * (At[d,i] + t*e[i]),
//     t = x_t[b,d], At[d,i] = sum_n EJ[i,n] NS[n,d], EJ[i,n] = sum_j ev[i,j,n],
//     e[i] = sum_n EJ[i,n]
//   Step 2 only needs i = 127: out[b,d] = relu((d!=127) * sig * (EJ[127,:]·s1))
//
// Round 5: single fused kernel, phases chained by device-scope atomics.
// Deadlock-safe by construction: __launch_bounds__(256,4) caps VGPR at 128
// (4 waves/EU) and LDS is 34.3 KB (4 blocks/CU) -> capacity 1024 blocks,
// grid is 657 -> all blocks co-resident, spins always make progress.
// Harness floor note: ~85 us/iter is reset (268 MB 0xAA ws fill ~41 us + input
// restores) — only ~14 us was ours entering this round.

#define KQ 1152  // 4608/4

__device__ __forceinline__ float wave_reduce64(float v) {
#pragma unroll
  for (int m = 32; m >= 1; m >>= 1) v += __shfl_xor(v, m);
  return v;
}
__device__ __forceinline__ float wave_reduce32(float v) {
#pragma unroll
  for (int m = 16; m >= 1; m >>= 1) v += __shfl_xor(v, m);
  return v;
}

// ws float offsets
#define WS_EJT 0        // 16384: EJT[n*128 + i] = EJ[i,n]
#define WS_E 16384      // 128:   e[i]
#define WS_EJ127 16512  // 128:   EJ[127, :]
#define WS_XT 16640     // 4096:  x_t[b*128 + d]
#define WS_OBD 20736    // 4096:  out[b*128 + d]
#define WS_CTR 24832    // 2 uint32 phase counters (memset to 0 each launch)

// Phase A: blocks 0..127   -> EJ row i -> EJT column, e[i], EJ127 row
// Phase B: blocks 128..383 -> x_t, one wave per 2b x 2d tile
// Phase C: blocks 384..511 -> per-d brain steps -> obd        (waits ctr0==384)
// Phase D: blocks 512..655 -> recreation 32f x 32b tiles       (waits ctr1==128)
//          block 656       -> scores
__global__ __launch_bounds__(256, 4) void brain_all(
    const float* __restrict__ ev, const float* __restrict__ x,
    const float* __restrict__ ipw, const float* __restrict__ ipb,
    const float* __restrict__ ns, const float* __restrict__ rw,
    const float* __restrict__ rb, const float* __restrict__ sw,
    const float* __restrict__ sb, float* __restrict__ ws,
    float* __restrict__ out) {
  __shared__ __align__(16) float smem[8576];  // 34.3 KB, phase-overlaid
  int tid = threadIdx.x, blk = blockIdx.x;
  unsigned* ctr = (unsigned*)(ws + WS_CTR);

  if (blk < 128) {  // ---- Phase A: EJ row i ----
    float4* sarr = (float4*)smem;
    int i = blk;
    int n4 = tid & 31, jg = tid >> 5;
    const float4* ev4 = (const float4*)ev;
    float4 acc = make_float4(0.f, 0.f, 0.f, 0.f);
#pragma unroll
    for (int jj = 0; jj < 16; ++jj) {
      int j = jg * 16 + jj;
      float4 v = ev4[i * 4096 + j * 32 + n4];
      acc.x += v.x; acc.y += v.y; acc.z += v.z; acc.w += v.w;
    }
    sarr[tid] = acc;
    __syncthreads();
    if (tid < 32) {
      float4 s = sarr[tid];
#pragma unroll
      for (int k = 1; k < 8; ++k) {
        float4 v = sarr[tid + 32 * k];
        s.x += v.x; s.y += v.y; s.z += v.z; s.w += v.w;
      }
      float* EJT = ws + WS_EJT;
      int n0 = tid * 4;
      EJT[(n0 + 0) * 128 + i] = s.x;
      EJT[(n0 + 1) * 128 + i] = s.y;
      EJT[(n0 + 2) * 128 + i] = s.z;
      EJT[(n0 + 3) * 128 + i] = s.w;
      if (i == 127) *(float4*)(ws + WS_EJ127 + n0) = s;
      float p = s.x + s.y + s.z + s.w;
      p = wave_reduce32(p);
      if (tid == 0) (ws + WS_E)[i] = p;
    }
    __syncthreads();
    if (tid == 0)
      __hip_atomic_fetch_add(ctr, 1u, __ATOMIC_RELEASE, __HIP_MEMORY_SCOPE_AGENT);
  } else if (blk < 384) {  // ---- Phase B: x_t 2x2 tile per wave ----
    int gw = (blk - 128) * 4 + (tid >> 6);
    int lane = tid & 63;
    int b0 = (gw >> 6) << 1, d0 = (gw & 63) << 1;
    const float4* x4 = (const float4*)x;
    const float4* w4 = (const float4*)ipw;
    float a00 = 0.f, a01 = 0.f, a10 = 0.f, a11 = 0.f;
#pragma unroll 4
    for (int kq = lane; kq < KQ; kq += 64) {
      float4 xa = x4[b0 * KQ + kq];
      float4 xb = x4[(b0 + 1) * KQ + kq];
      float4 wa = w4[d0 * KQ + kq];
      float4 wb = w4[(d0 + 1) * KQ + kq];
      a00 += xa.x * wa.x + xa.y * wa.y + xa.z * wa.z + xa.w * wa.w;
      a01 += xa.x * wb.x + xa.y * wb.y + xa.z * wb.z + xa.w * wb.w;
      a10 += xb.x * wa.x + xb.y * wa.y + xb.z * wa.z + xb.w * wa.w;
      a11 += xb.x * wb.x + xb.y * wb.y + xb.z * wb.z + xb.w * wb.w;
    }
    a00 = wave_reduce64(a00);
    a01 = wave_reduce64(a01);
    a10 = wave_reduce64(a10);
    a11 = wave_reduce64(a11);
    if (lane == 0) {
      float* xt = ws + WS_XT;
      xt[b0 * 128 + d0] = a00 + ipb[d0];
      xt[b0 * 128 + d0 + 1] = a01 + ipb[d0 + 1];
      xt[(b0 + 1) * 128 + d0] = a10 + ipb[d0];
      xt[(b0 + 1) * 128 + d0 + 1] = a11 + ipb[d0 + 1];
    }
    __syncthreads();
    if (tid == 0)
      __hip_atomic_fetch_add(ctr, 1u, __ATOMIC_RELEASE, __HIP_MEMORY_SCOPE_AGENT);
  } else if (blk < 512) {  // ---- Phase C: per-d brain steps ----
    float* nscol = smem;          // 128
    float* xts = smem + 128;      // 32
    float* at2 = smem + 160;      // 2 x 128
    float* Atf = smem + 416;      // 128
    float* csum_s = smem + 544;   // 1
    int d = blk - 384;
    if (tid < 128) nscol[tid] = ns[tid * 128 + d];
    if (tid == 0) {
      while (__hip_atomic_load(ctr, __ATOMIC_ACQUIRE, __HIP_MEMORY_SCOPE_AGENT) < 384u)
        __builtin_amdgcn_s_sleep(1);
    }
    __syncthreads();
    if (tid >= 128 && tid < 160) xts[tid - 128] = (ws + WS_XT)[(tid - 128) * 128 + d];
    {
      int i = tid & 127, h = tid >> 7;
      const float* EJTp = ws + WS_EJT + h * 64 * 128 + i;
      const float* nsr = &nscol[h * 64];
      float a = 0.f;
#pragma unroll 8
      for (int n = 0; n < 64; ++n) a += EJTp[n * 128] * nsr[n];
      at2[h * 128 + i] = a;
    }
    if (tid < 64) {
      float cl = nscol[tid] + nscol[tid + 64];
      cl = wave_reduce64(cl);
      if (tid == 0) *csum_s = cl;
    }
    __syncthreads();
    if (tid < 128) Atf[tid] = at2[tid] + at2[128 + tid];
    __syncthreads();
    int wv = tid >> 6, l = tid & 63;
    float a0 = Atf[l], a1 = Atf[l + 64];
    float e0 = (ws + WS_E)[l], e1 = (ws + WS_E)[l + 64];
    float q0 = (ws + WS_EJ127)[l], q1 = (ws + WS_EJ127)[l + 64];
    float csum = *csum_s;
    bool z0 = (l == d), z1 = (l + 64 == d);
    float* obd = ws + WS_OBD;
#pragma unroll
    for (int bb = 0; bb < 8; ++bb) {
      int b = wv * 8 + bb;
      float t = xts[b];
      float s0s = csum + 128.f * t;
      float v0 = s0s * (a0 + t * e0);
      float v1 = s0s * (a1 + t * e1);
      v0 = z0 ? 0.f : fmaxf(v0, 0.f);  // step-1 mask + relu
      v1 = z1 ? 0.f : fmaxf(v1, 0.f);
      float sig = wave_reduce64(v0 + v1);
      float y = wave_reduce64(q0 * v0 + q1 * v1);
      if (l == 0) {
        float m2 = sig * y;
        if (d == 127) m2 = 0.f;  // step-2 mask (i=127)
        obd[b * 128 + d] = fmaxf(m2, 0.f);
      }
    }
    __syncthreads();
    if (tid == 0)
      __hip_atomic_fetch_add(ctr + 1, 1u, __ATOMIC_RELEASE, __HIP_MEMORY_SCOPE_AGENT);
  } else if (blk < 656) {  // ---- Phase D: recreation tiles ----
    float* rwlds = smem;          // 32 x 136
    float* obdT = smem + 4352;    // 128 x 33
    int f0 = (blk - 512) * 32;
    const float4* rw4 = (const float4*)rw;
#pragma unroll
    for (int it = 0; it < 4; ++it) {
      int q = tid + 256 * it;
      int f = q >> 5, n4 = q & 31;
      *(float4*)&rwlds[f * 136 + n4 * 4] = rw4[f0 * 32 + q];
    }
    if (tid == 0) {
      while (__hip_atomic_load(ctr + 1, __ATOMIC_ACQUIRE, __HIP_MEMORY_SCOPE_AGENT) < 128u)
        __builtin_amdgcn_s_sleep(1);
    }
    __syncthreads();
    const float* obd = ws + WS_OBD;
#pragma unroll
    for (int it = 0; it < 16; ++it) {
      int q = tid + 256 * it;
      int b = q >> 7, dd = q & 127;
      obdT[dd * 33 + b] = obd[q];
    }
    __syncthreads();
    int f = tid >> 3, bg = tid & 7;
    float acc[4] = {0.f, 0.f, 0.f, 0.f};
#pragma unroll 4
    for (int d = 0; d < 128; ++d) {
      float w = rwlds[f * 136 + d];
#pragma unroll
      for (int k = 0; k < 4; ++k) acc[k] += w * obdT[d * 33 + bg * 4 + k];
    }
    float bias = rb[f0 + f];
#pragma unroll
    for (int k = 0; k < 4; ++k) out[(bg * 4 + k) * 4608 + f0 + f] = acc[k] + bias;
  } else {  // ---- block 656: scores ----
    if (tid == 0) {
      while (__hip_atomic_load(ctr + 1, __ATOMIC_ACQUIRE, __HIP_MEMORY_SCOPE_AGENT) < 128u)
        __builtin_amdgcn_s_sleep(1);
    }
    __syncthreads();
    const float* obd = ws + WS_OBD;
    int b = tid >> 3, l8 = tid & 7;
    float acc = 0.f;
    for (int d = l8; d < 128; d += 8) acc += obd[b * 128 + d] * sw[d];
    acc += __shfl_xor(acc, 1);
    acc += __shfl_xor(acc, 2);
    acc += __shfl_xor(acc, 4);
    if (l8 == 0) out[147456 + b] = acc + sb[0];
  }
}

extern "C" void kernel_launch(void* const* d_in, const int* in_sizes, int n_in,
                              void* d_out, int out_size, void* d_ws, size_t ws_size,
                              hipStream_t stream) {
  const float* x   = (const float*)d_in[0];   // (32, 4608)
  const float* ipw = (const float*)d_in[1];   // (128, 4608)
  const float* ipb = (const float*)d_in[2];   // (128,)
  const float* ns  = (const float*)d_in[3];   // (128, 128)
  const float* ev  = (const float*)d_in[4];   // (128, 128, 128)
  const float* rw  = (const float*)d_in[5];   // (4608, 128)
  const float* rb  = (const float*)d_in[6];   // (4608,)
  const float* sw  = (const float*)d_in[7];   // (1, 128)
  const float* sb  = (const float*)d_in[8];   // (1,)
  float* out = (float*)d_out;                 // 147456 recreation + 32 scores
  float* ws = (float*)d_ws;                   // uses 24834 floats (~99 KB)

  // zero the two phase counters (graph-capturable async memset node)
  hipMemsetAsync((char*)d_ws + WS_CTR * sizeof(float), 0, 2 * sizeof(unsigned), stream);
  brain_all<<<657, 256, 0, stream>>>(ev, x, ipw, ipb, ns, rw, rb, sw, sb, ws, out);
}

// Round 6
// 98.267 us; speedup vs baseline: 1.8059x; 1.8059x over previous
//
#include <hip/hip_runtime.h>

// AGMBrain: N=128, B=32, IN_FEAT=4608, grid_size=3, num_candidates=8, n_steps=2
//
// Algebraic reduction (verified rounds 1-5):
//   einsum 'bdij,bdn->bdi' factorizes: messages[b,d,i] =
//     (sum_j T[b,d,i,j]) * (sum_n s[b,d,n])
//   Step 1 closed form: m1[b,d,i] = (colsum[d] + 128 t) * (At[d,i] + t*e[i]),
//     t = x_t[b,d], At[d,i] = sum_n EJ[i,n] NS[n,d], EJ[i,n] = sum_j ev[i,j,n],
//     e[i] = sum_n EJ[i,n]
//   Step 2 only needs i = 127: out[b,d] = relu((d!=127) * sig * (EJ[127,:]·s1))
//
// Round 6: REVERT round-5 atomic fusion (device-scope release/acquire spin cost
// ~100 us of TCC invalidate/writeback serialization — 3 plain launches are far
// cheaper). Back to round-4 3-kernel pipeline + refinement: At GEMV fused into
// phase A (block i owns EJ[i,:] in LDS -> computes VT[d,i] column directly),
// so k2 is a near-trivial per-d kernel.
// Harness floor note: ~85 us/iter is reset (268 MB 0xAA ws fill ~41 us + input
// restores); controllable share ~14 us entering this round.

#define KQ 1152  // 4608/4

__device__ __forceinline__ float wave_reduce64(float v) {
#pragma unroll
  for (int m = 32; m >= 1; m >>= 1) v += __shfl_xor(v, m);
  return v;
}
__device__ __forceinline__ float wave_reduce32(float v) {
#pragma unroll
  for (int m = 16; m >= 1; m >>= 1) v += __shfl_xor(v, m);
  return v;
}

// ws float offsets
#define WS_VT 0        // 16384: VT[d*128 + i] = At[d,i]
#define WS_E 16384     // 128:   e[i]
#define WS_EJ127 16512 // 128:   EJ[127, :]
#define WS_CS 16640    // 128:   colsum[d]
#define WS_XT 16768    // 4096:  x_t[b*128 + d]
#define WS_OBD 20864   // 4096:  out[b*128 + d]
// total 24960 floats = 100 KB

// K1: blocks 0..127  -> EJ row i (reduce over j), then At GEMV row:
//                       VT[d*128+i] = sum_n EJ[i,n] NS[n,d]; e[i]; EJ127;
//                       block 0 also emits colsum[d] = sum_n NS[n,d]
//     blocks 128..383 -> x_t, one wave per 2b x 2d tile
__global__ __launch_bounds__(256) void k1_pre(const float* __restrict__ ev,
                                              const float* __restrict__ ns,
                                              const float* __restrict__ x,
                                              const float* __restrict__ ipw,
                                              const float* __restrict__ ipb,
                                              float* __restrict__ ws) {
  int tid = threadIdx.x, blk = blockIdx.x;
  if (blk < 128) {
    __shared__ __align__(16) float4 sarr[256];
    __shared__ __align__(16) float ej[128];
    __shared__ float at2[2][128];
    __shared__ float cs2[2][128];
    int i = blk;
    int n4 = tid & 31, jg = tid >> 5;  // 8 j-groups x 16 j each
    const float4* ev4 = (const float4*)ev;
    float4 acc = make_float4(0.f, 0.f, 0.f, 0.f);
#pragma unroll
    for (int jj = 0; jj < 16; ++jj) {
      int j = jg * 16 + jj;
      float4 v = ev4[i * 4096 + j * 32 + n4];
      acc.x += v.x; acc.y += v.y; acc.z += v.z; acc.w += v.w;
    }
    sarr[tid] = acc;
    __syncthreads();
    if (tid < 32) {
      float4 s = sarr[tid];
#pragma unroll
      for (int k = 1; k < 8; ++k) {
        float4 v = sarr[tid + 32 * k];
        s.x += v.x; s.y += v.y; s.z += v.z; s.w += v.w;
      }
      int n0 = tid * 4;
      *(float4*)&ej[n0] = s;                           // EJ row -> LDS
      if (i == 127) *(float4*)(ws + WS_EJ127 + n0) = s;
      float p = s.x + s.y + s.z + s.w;
      p = wave_reduce32(p);
      if (tid == 0) (ws + WS_E)[i] = p;
    }
    __syncthreads();
    // At GEMV: d = tid&127, n-range split over h
    int d = tid & 127, h = tid >> 7;
    {
      const float* nsp = ns + h * 64 * 128 + d;   // coalesced across d
      const float* ejp = &ej[h * 64];             // broadcast reads
      float a = 0.f;
#pragma unroll 8
      for (int n = 0; n < 64; ++n) a += ejp[n] * nsp[n * 128];
      at2[h][d] = a;
    }
    if (i == 0) {  // colsum only in block 0
      const float* nsp = ns + h * 64 * 128 + d;
      float c = 0.f;
#pragma unroll 8
      for (int n = 0; n < 64; ++n) c += nsp[n * 128];
      cs2[h][d] = c;
    }
    __syncthreads();
    if (tid < 128) {
      (ws + WS_VT)[tid * 128 + i] = at2[0][tid] + at2[1][tid];  // scatter column
      if (i == 0) (ws + WS_CS)[tid] = cs2[0][tid] + cs2[1][tid];
    }
  } else {
    int gw = (blk - 128) * 4 + (tid >> 6);  // 0..1023 tiles
    int lane = tid & 63;
    int b0 = (gw >> 6) << 1, d0 = (gw & 63) << 1;
    const float4* x4 = (const float4*)x;
    const float4* w4 = (const float4*)ipw;
    float a00 = 0.f, a01 = 0.f, a10 = 0.f, a11 = 0.f;
#pragma unroll 6
    for (int kq = lane; kq < KQ; kq += 64) {
      float4 xa = x4[b0 * KQ + kq];
      float4 xb = x4[(b0 + 1) * KQ + kq];
      float4 wa = w4[d0 * KQ + kq];
      float4 wb = w4[(d0 + 1) * KQ + kq];
      a00 += xa.x * wa.x + xa.y * wa.y + xa.z * wa.z + xa.w * wa.w;
      a01 += xa.x * wb.x + xa.y * wb.y + xa.z * wb.z + xa.w * wb.w;
      a10 += xb.x * wa.x + xb.y * wa.y + xb.z * wa.z + xb.w * wa.w;
      a11 += xb.x * wb.x + xb.y * wb.y + xb.z * wb.z + xb.w * wb.w;
    }
    a00 = wave_reduce64(a00);
    a01 = wave_reduce64(a01);
    a10 = wave_reduce64(a10);
    a11 = wave_reduce64(a11);
    if (lane == 0) {
      float* xt = ws + WS_XT;
      xt[b0 * 128 + d0] = a00 + ipb[d0];
      xt[b0 * 128 + d0 + 1] = a01 + ipb[d0 + 1];
      xt[(b0 + 1) * 128 + d0] = a10 + ipb[d0];
      xt[(b0 + 1) * 128 + d0 + 1] = a11 + ipb[d0 + 1];
    }
  }
}

// K2: one tiny block per d: coalesced VT column + e + ej127 + colsum scalar,
// then register-resident step1+step2 for all 32 b.
__global__ __launch_bounds__(256) void k2_brain(float* __restrict__ ws) {
  __shared__ float xts[32];
  int tid = threadIdx.x, d = blockIdx.x;
  if (tid < 32) xts[tid] = (ws + WS_XT)[tid * 128 + d];
  __syncthreads();
  int wv = tid >> 6, l = tid & 63;
  float a0 = (ws + WS_VT)[d * 128 + l], a1 = (ws + WS_VT)[d * 128 + 64 + l];
  float e0 = (ws + WS_E)[l], e1 = (ws + WS_E)[l + 64];
  float q0 = (ws + WS_EJ127)[l], q1 = (ws + WS_EJ127)[l + 64];
  float csum = (ws + WS_CS)[d];
  bool z0 = (l == d), z1 = (l + 64 == d);
  float* obd = ws + WS_OBD;
#pragma unroll
  for (int bb = 0; bb < 8; ++bb) {
    int b = wv * 8 + bb;
    float t = xts[b];
    float s0s = csum + 128.f * t;
    float v0 = s0s * (a0 + t * e0);
    float v1 = s0s * (a1 + t * e1);
    v0 = z0 ? 0.f : fmaxf(v0, 0.f);  // step-1 mask + relu
    v1 = z1 ? 0.f : fmaxf(v1, 0.f);
    float sig = wave_reduce64(v0 + v1);
    float y = wave_reduce64(q0 * v0 + q1 * v1);
    if (l == 0) {
      float m2 = sig * y;
      if (d == 127) m2 = 0.f;  // step-2 mask (i=127)
      obd[b * 128 + d] = fmaxf(m2, 0.f);
    }
  }
}

// K3: blocks 0..143: recreation tile 32 f x 32 b; block 144: scores
__global__ __launch_bounds__(256) void k3_proj(const float* __restrict__ rw,
                                               const float* __restrict__ rb,
                                               const float* __restrict__ sw,
                                               const float* __restrict__ sb,
                                               const float* __restrict__ ws,
                                               float* __restrict__ out) {
  const float* obd = ws + WS_OBD;
  int tid = threadIdx.x;
  int blk = blockIdx.x;
  if (blk < 144) {
    __shared__ __align__(16) float rwlds[32 * 136];
    __shared__ float obdT[128 * 33];
    int f0 = blk * 32;
    const float4* rw4 = (const float4*)rw;
#pragma unroll
    for (int it = 0; it < 4; ++it) {
      int q = tid + 256 * it;
      int f = q >> 5, n4 = q & 31;
      *(float4*)&rwlds[f * 136 + n4 * 4] = rw4[f0 * 32 + q];
    }
#pragma unroll
    for (int it = 0; it < 16; ++it) {
      int q = tid + 256 * it;
      int b = q >> 7, dd = q & 127;
      obdT[dd * 33 + b] = obd[q];
    }
    __syncthreads();
    int f = tid >> 3, bg = tid & 7;
    float acc[4] = {0.f, 0.f, 0.f, 0.f};
#pragma unroll 4
    for (int d = 0; d < 128; ++d) {
      float w = rwlds[f * 136 + d];
#pragma unroll
      for (int k = 0; k < 4; ++k) acc[k] += w * obdT[d * 33 + bg * 4 + k];
    }
    float bias = rb[f0 + f];
#pragma unroll
    for (int k = 0; k < 4; ++k) out[(bg * 4 + k) * 4608 + f0 + f] = acc[k] + bias;
  } else {
    int b = tid >> 3, l8 = tid & 7;
    float acc = 0.f;
    for (int d = l8; d < 128; d += 8) acc += obd[b * 128 + d] * sw[d];
    acc += __shfl_xor(acc, 1);
    acc += __shfl_xor(acc, 2);
    acc += __shfl_xor(acc, 4);
    if (l8 == 0) out[147456 + b] = acc + sb[0];
  }
}

extern "C" void kernel_launch(void* const* d_in, const int* in_sizes, int n_in,
                              void* d_out, int out_size, void* d_ws, size_t ws_size,
                              hipStream_t stream) {
  const float* x   = (const float*)d_in[0];   // (32, 4608)
  const float* ipw = (const float*)d_in[1];   // (128, 4608)
  const float* ipb = (const float*)d_in[2];   // (128,)
  const float* ns  = (const float*)d_in[3];   // (128, 128)
  const float* ev  = (const float*)d_in[4];   // (128, 128, 128)
  const float* rw  = (const float*)d_in[5];   // (4608, 128)
  const float* rb  = (const float*)d_in[6];   // (4608,)
  const float* sw  = (const float*)d_in[7];   // (1, 128)
  const float* sb  = (const float*)d_in[8];   // (1,)
  float* out = (float*)d_out;                 // 147456 recreation + 32 scores
  float* ws = (float*)d_ws;                   // uses 24960 floats (~100 KB)

  k1_pre<<<384, 256, 0, stream>>>(ev, ns, x, ipw, ipb, ws);
  k2_brain<<<128, 256, 0, stream>>>(ws);
  k3_proj<<<145, 256, 0, stream>>>(rw, rb, sw, sb, ws, out);
}